// Round 2
// baseline (468.790 us; speedup 1.0000x reference)
//
#include <hip/hip_runtime.h>
#include <hip/hip_bf16.h>

typedef __bf16 bf16_t;
typedef __bf16 bf16x8 __attribute__((ext_vector_type(8)));
typedef float  f32x4  __attribute__((ext_vector_type(4)));

#define MFMA16(A,B,C) __builtin_amdgcn_mfma_f32_16x16x32_bf16((A),(B),(C),0,0,0)

constexpr int Bn = 2, Cc = 128, Hh = 64, Wd = 64;
constexpr int N  = Hh * Wd;      // 4096 tokens per batch
constexpr int T  = Bn * N;       // 8192 tokens total
constexpr int D  = 2 * Cc;       // 256 = [real | imag] channels
constexpr int NSP = 8;           // key splits
constexpr float EPS = 1e-5f;
constexpr float SCL = 0.08838834764831845f * 1.4426950408889634f; // C^-0.5 * log2(e)

// 64-row x 256-ch bf16 tile image (32KB): elem(row, ch) at
//   row*512 + ((ch>>3) ^ (row&31))*16 + (ch&7)*2
// -> global_load_lds identity copy; fragment reads bank-uniform.
__device__ __forceinline__ size_t tile_addr(int row, int ch) {
    return (size_t)row * 512 + (size_t)((((ch >> 3) ^ (row & 31)) * 16) + (ch & 7) * 2);
}
// V tile: [ch 256][key 64]: ch*128 + ((key>>3) ^ (ch&7))*16 + (key&7)*2
__device__ __forceinline__ size_t vtile_addr(int ch, int key) {
    return (size_t)ch * 128 + (size_t)(((((key >> 3) ^ (ch & 7))) * 16) + (key & 7) * 2);
}

__device__ __forceinline__ void gl16(const void* g, void* l) {
    __builtin_amdgcn_global_load_lds(
        (const __attribute__((address_space(1))) void*)g,
        (__attribute__((address_space(3))) void*)l, 16, 0, 0);
}

// ---------------- kernel 1: BN stats -> per-channel scale/shift ----------------
__global__ void k_bnstats(const float* __restrict__ x, const float* __restrict__ bn_w,
                          const float* __restrict__ bn_b, float4* __restrict__ ss) {
    int c = blockIdx.x;          // 128
    int tid = threadIdx.x;       // 256
    float sr = 0.f, si = 0.f, qr = 0.f, qi = 0.f;
    for (int b = 0; b < Bn; ++b) {
        const float2* p = (const float2*)x + (size_t)(b * Cc + c) * N;
        for (int hw = tid; hw < N; hw += 256) {
            float2 v = p[hw];
            sr += v.x; si += v.y; qr += v.x * v.x; qi += v.y * v.y;
        }
    }
    #pragma unroll
    for (int d = 32; d >= 1; d >>= 1) {
        sr += __shfl_xor(sr, d); si += __shfl_xor(si, d);
        qr += __shfl_xor(qr, d); qi += __shfl_xor(qi, d);
    }
    __shared__ float red[4][4];
    int w = tid >> 6;
    if ((tid & 63) == 0) { red[w][0] = sr; red[w][1] = si; red[w][2] = qr; red[w][3] = qi; }
    __syncthreads();
    if (tid == 0) {
        sr = red[0][0] + red[1][0] + red[2][0] + red[3][0];
        si = red[0][1] + red[1][1] + red[2][1] + red[3][1];
        qr = red[0][2] + red[1][2] + red[2][2] + red[3][2];
        qi = red[0][3] + red[1][3] + red[2][3] + red[3][3];
        const float inv = 1.0f / (float)(Bn * N);
        float mr = sr * inv, mi = si * inv;
        float vr = qr * inv - mr * mr, vi = qi * inv - mi * mi;
        float scr = bn_w[c * 2 + 0] * rsqrtf(vr + EPS);
        float sci = bn_w[c * 2 + 1] * rsqrtf(vi + EPS);
        ss[c] = make_float4(scr, bn_b[c * 2 + 0] - mr * scr,
                            sci, bn_b[c * 2 + 1] - mi * sci);
    }
}

// ---- kernel 2: normalize; xn fp32 -> d_out (residual), bf16 tile images -> XNg
__global__ void k_norm(const float* __restrict__ x, const float4* __restrict__ ss,
                       float* __restrict__ xn_out, char* __restrict__ XNg) {
    __shared__ __align__(16) char Tsh[32768];
    int blk = blockIdx.x;        // 128 token tiles
    int b = blk >> 6, hw0 = (blk & 63) * 64;
    int tid = threadIdx.x;
    const float2* xin = (const float2*)x;
    float2* xo = (float2*)xn_out;
    #pragma unroll
    for (int it = 0; it < 32; ++it) {
        int idx = it * 256 + tid;
        int c = idx >> 6, hw = idx & 63;
        size_t gi = (size_t)(b * Cc + c) * N + hw0 + hw;
        float2 v = xin[gi];
        float4 s = ss[c];
        float xr = v.x * s.x + s.y;
        float xi = v.y * s.z + s.w;
        xo[gi] = make_float2(xr, xi);
        *(bf16_t*)(Tsh + tile_addr(hw, c))       = (bf16_t)xr;
        *(bf16_t*)(Tsh + tile_addr(hw, c + 128)) = (bf16_t)xi;
    }
    __syncthreads();
    #pragma unroll
    for (int it = 0; it < 8; ++it) {
        int idx = it * 256 + tid;
        *(uint4*)(XNg + (size_t)blk * 32768 + idx * 16) = *(const uint4*)(Tsh + idx * 16);
    }
}

// ---- kernel 3: combined weights -> 12 swizzled tiles [outcol 64][k 256] + bias
__global__ void k_prep(const float* __restrict__ wq, const float* __restrict__ wk,
                       const float* __restrict__ wv, const float* __restrict__ bq,
                       const float* __restrict__ bk, const float* __restrict__ bv,
                       char* __restrict__ Wg, float* __restrict__ bt) {
    int o = blockIdx.x;      // 768 = [Qr Qi Kr Ki Vr Vi] x128
    int k = threadIdx.x;     // 256
    int proj = o >> 8, oc = o & 255;
    const float* wsrc = proj == 0 ? wq : (proj == 1 ? wk : wv);
    const float* bsrc = proj == 0 ? bq : (proj == 1 ? bk : bv);
    int co = oc >> 7, oo = oc & 127;
    int c = k & 127, kc = k >> 7;
    float val;
    if (co == 0) val = (kc == 0) ? wsrc[(oo * 128 + c) * 2 + 0] : -wsrc[(oo * 128 + c) * 2 + 1];
    else         val = (kc == 0) ? wsrc[(oo * 128 + c) * 2 + 1] :  wsrc[(oo * 128 + c) * 2 + 0];
    int tile = o >> 6, row = o & 63;
    *(bf16_t*)(Wg + (size_t)tile * 32768 + tile_addr(row, k)) = (bf16_t)val;
    if (k == 0) bt[o] = bsrc[oo * 2 + co];
}

// ---- kernel 4: QKV GEMM [8192x256]@[256x768]; Q token-major, K/V tile images
__global__ __launch_bounds__(256) void k_qkv(const char* __restrict__ XNg,
        const char* __restrict__ Wg, const float* __restrict__ bt,
        bf16_t* __restrict__ Qg, char* __restrict__ Kg, char* __restrict__ Vg) {
    __shared__ __align__(16) char Xsh[32768];
    __shared__ __align__(16) char Wsh[32768];
    int mx = blockIdx.x, ny = blockIdx.y;   // 128 x 12
    int tid = threadIdx.x;
    int w = tid >> 6, lane = tid & 63, n15 = lane & 15, quad = lane >> 4;
    const char* xs = XNg + (size_t)mx * 32768;
    const char* wsp = Wg + (size_t)ny * 32768;
    #pragma unroll
    for (int i = 0; i < 8; ++i) {
        int off = (w * 8 + i) * 1024 + lane * 16;
        gl16(xs + off, Xsh + off);
        gl16(wsp + off, Wsh + off);
    }
    __syncthreads();
    int arow = w * 16 + n15, aswz = arow & 31;
    const char* abase = Xsh + arow * 512;
    f32x4 acc[4] = {};
    #pragma unroll
    for (int ks = 0; ks < 8; ++ks) {
        bf16x8 a = *(const bf16x8*)(abase + ((ks * 4 + quad) ^ aswz) * 16);
        #pragma unroll
        for (int t = 0; t < 4; ++t) {
            int brow = t * 16 + n15;
            bf16x8 bw = *(const bf16x8*)(Wsh + brow * 512 + ((ks * 4 + quad) ^ (brow & 31)) * 16);
            acc[t] = MFMA16(a, bw, acc[t]);
        }
    }
    int proj = ny >> 2;            // 0=Q 1=K 2=V
    int jb = (ny & 3) * 64;
    #pragma unroll
    for (int t = 0; t < 4; ++t) {
        int j = jb + t * 16 + n15;
        float bias = bt[ny * 64 + t * 16 + n15];
        #pragma unroll
        for (int r = 0; r < 4; ++r) {
            int tk = mx * 64 + w * 16 + quad * 4 + r;
            float v = acc[t][r] + bias;
            if (proj == 0) {
                Qg[(size_t)tk * D + j] = (bf16_t)v;
            } else {
                int bb = tk >> 12, n = tk & (N - 1);
                int ktile = n >> 6, rr = n & 63;
                size_t tb = (size_t)(bb * 64 + ktile) * 32768;
                if (proj == 1) *(bf16_t*)(Kg + tb + tile_addr(rr, j)) = (bf16_t)v;
                else           *(bf16_t*)(Vg + tb + vtile_addr(j, rr)) = (bf16_t)v;
            }
        }
    }
}

// ---- kernel 5: flash attention. BR=128 (4 waves x 32 rows), BC=64, split 8.
// K/V staged via global_load_lds (identity tile copy); P strips alias Ksh.
__global__ __launch_bounds__(256, 2) void k_attn(const bf16_t* __restrict__ Qg,
        const char* __restrict__ Kg, const char* __restrict__ Vg,
        bf16_t* __restrict__ Opb, float* __restrict__ Mp, float* __restrict__ Lp) {
    __shared__ __align__(16) char Ksh[32768];
    __shared__ __align__(16) char Vsh[32768];
    int bid = blockIdx.x;               // 512 = 2b x 8sp x 32qt
    int qt = bid & 31, sp = (bid >> 5) & 7, b = bid >> 8;
    int tid = threadIdx.x;
    int w = tid >> 6, lane = tid & 63, n15 = lane & 15, quad = lane >> 4;

    // preload Q fragments for this wave's 32 rows (2 groups of 16)
    bf16x8 qf[2][8];
    const bf16_t* q0 = Qg + (size_t)(b * N + qt * 128 + w * 32 + n15) * D;
    #pragma unroll
    for (int ks = 0; ks < 8; ++ks) {
        qf[0][ks] = *(const bf16x8*)(q0 + ks * 32 + quad * 8);
        qf[1][ks] = *(const bf16x8*)(q0 + 16 * D + ks * 32 + quad * 8);
    }

    f32x4 o[2][16] = {};
    float m_[2][4], l_[2][4];
    #pragma unroll
    for (int g = 0; g < 2; ++g)
        #pragma unroll
        for (int r = 0; r < 4; ++r) { m_[g][r] = -1e30f; l_[g][r] = 0.f; }

    char* Pw = Ksh + w * 4608;          // 32 rows x 72 bf16, wave-private

    for (int kt = 0; kt < 8; ++kt) {
        size_t tb = (size_t)(b * 64 + sp * 8 + kt) * 32768;
        __syncthreads();                              // (A) prev iter fully consumed
        #pragma unroll
        for (int i = 0; i < 8; ++i) {
            int off = (w * 8 + i) * 1024 + lane * 16;
            gl16(Kg + tb + off, Ksh + off);
            gl16(Vg + tb + off, Vsh + off);
        }
        __syncthreads();                              // (B) staging landed

        f32x4 s[2][4] = {};
        #pragma unroll
        for (int t = 0; t < 4; ++t) {
            int row = t * 16 + n15, swz = row & 31;
            const char* rb = Ksh + row * 512;
            #pragma unroll
            for (int ks = 0; ks < 8; ++ks) {
                bf16x8 kf = *(const bf16x8*)(rb + ((ks * 4 + quad) ^ swz) * 16);
                s[0][t] = MFMA16(qf[0][ks], kf, s[0][t]);
                s[1][t] = MFMA16(qf[1][ks], kf, s[1][t]);
            }
        }
        __syncthreads();                              // (C) all K reads done; P may overwrite

        float al[2][4];
        int need = 0;
        #pragma unroll
        for (int g = 0; g < 2; ++g) {
            float rmax[4];
            #pragma unroll
            for (int r = 0; r < 4; ++r)
                rmax[r] = fmaxf(fmaxf(s[g][0][r], s[g][1][r]), fmaxf(s[g][2][r], s[g][3][r]));
            #pragma unroll
            for (int d = 1; d < 16; d <<= 1) {
                #pragma unroll
                for (int r = 0; r < 4; ++r) rmax[r] = fmaxf(rmax[r], __shfl_xor(rmax[r], d));
            }
            #pragma unroll
            for (int r = 0; r < 4; ++r) {
                float mn = fmaxf(m_[g][r], rmax[r] * SCL);
                al[g][r] = exp2f(m_[g][r] - mn);
                need |= (mn > m_[g][r]);
                m_[g][r] = mn;
            }
        }
        if (__any(need)) {
            #pragma unroll
            for (int g = 0; g < 2; ++g)
                #pragma unroll
                for (int ct = 0; ct < 16; ++ct)
                    #pragma unroll
                    for (int r = 0; r < 4; ++r) o[g][ct][r] *= al[g][r];
        }
        #pragma unroll
        for (int g = 0; g < 2; ++g) {
            float rs[4] = {0.f, 0.f, 0.f, 0.f};
            #pragma unroll
            for (int t = 0; t < 4; ++t) {
                #pragma unroll
                for (int r = 0; r < 4; ++r) {
                    float p = exp2f(s[g][t][r] * SCL - m_[g][r]);
                    s[g][t][r] = p;
                    rs[r] += p;
                }
            }
            #pragma unroll
            for (int d = 1; d < 16; d <<= 1) {
                #pragma unroll
                for (int r = 0; r < 4; ++r) rs[r] += __shfl_xor(rs[r], d);
            }
            #pragma unroll
            for (int r = 0; r < 4; ++r) l_[g][r] = l_[g][r] * al[g][r] + rs[r];
            // write P strip (C-layout -> row-major bf16, pitch 72)
            #pragma unroll
            for (int t = 0; t < 4; ++t)
                #pragma unroll
                for (int r = 0; r < 4; ++r)
                    *(bf16_t*)(Pw + ((g * 16 + quad * 4 + r) * 72 + t * 16 + n15) * 2) =
                        (bf16_t)s[g][t][r];
        }
        // PV: o[g][ct] += P[g] x V
        #pragma unroll
        for (int k2 = 0; k2 < 2; ++k2) {
            bf16x8 pa0 = *(const bf16x8*)(Pw + (n15 * 72 + k2 * 32 + quad * 8) * 2);
            bf16x8 pa1 = *(const bf16x8*)(Pw + (((16 + n15) * 72) + k2 * 32 + quad * 8) * 2);
            #pragma unroll
            for (int ct = 0; ct < 16; ++ct) {
                int ch = ct * 16 + n15;
                bf16x8 bv = *(const bf16x8*)(Vsh + ch * 128 + ((k2 * 4 + quad) ^ (ch & 7)) * 16);
                o[0][ct] = MFMA16(pa0, bv, o[0][ct]);
                o[1][ct] = MFMA16(pa1, bv, o[1][ct]);
            }
        }
    }
    // epilogue: unnormalized O (bf16) + m, l per split
    int tok0 = b * N + qt * 128 + w * 32;
    #pragma unroll
    for (int g = 0; g < 2; ++g) {
        #pragma unroll
        for (int ct = 0; ct < 16; ++ct)
            #pragma unroll
            for (int r = 0; r < 4; ++r)
                Opb[((size_t)sp * T + tok0 + g * 16 + quad * 4 + r) * D + ct * 16 + n15] =
                    (bf16_t)o[g][ct][r];
        if (n15 == 0) {
            #pragma unroll
            for (int r = 0; r < 4; ++r) {
                Mp[sp * T + tok0 + g * 16 + quad * 4 + r] = m_[g][r];
                Lp[sp * T + tok0 + g * 16 + quad * 4 + r] = l_[g][r];
            }
        }
    }
}

// ---- kernel 6: combine splits, normalize, residual out = xn + gamma * O ----
__global__ void k_comb(const bf16_t* __restrict__ Opb, const float* __restrict__ Mp,
                       const float* __restrict__ Lp, const float* __restrict__ gamma,
                       float* __restrict__ out) {
    __shared__ float wts[NSP][32];
    __shared__ float Ot[256 * 33];
    int blk = blockIdx.x;                // 256 blocks x 32 tokens
    int b = blk >> 7, hw0 = (blk & 127) * 32;
    int tok0 = b * N + hw0;
    int tid = threadIdx.x;
    if (tid < 32) {
        float m[NSP], M = -1e30f;
        #pragma unroll
        for (int s = 0; s < NSP; ++s) { m[s] = Mp[s * T + tok0 + tid]; M = fmaxf(M, m[s]); }
        float Z = 0.f, wv[NSP];
        #pragma unroll
        for (int s = 0; s < NSP; ++s) {
            wv[s] = exp2f(m[s] - M);
            Z += Lp[s * T + tok0 + tid] * wv[s];
        }
        float iz = 1.0f / Z;
        #pragma unroll
        for (int s = 0; s < NSP; ++s) wts[s][tid] = wv[s] * iz;
    }
    __syncthreads();
    #pragma unroll
    for (int i = 0; i < 32; ++i) {
        int idx = i * 256 + tid;
        int tk = idx >> 8, ch = idx & 255;
        size_t base = (size_t)(tok0 + tk) * D + ch;
        float acc = 0.f;
        #pragma unroll
        for (int s = 0; s < NSP; ++s)
            acc += (float)Opb[(size_t)s * T * D + base] * wts[s][tk];
        Ot[ch * 33 + tk] = acc;
    }
    __syncthreads();
    float g = gamma[0];
    float2* xo = (float2*)out;
    #pragma unroll
    for (int i = 0; i < 16; ++i) {
        int linear = i * 256 + tid;
        int c = linear >> 5, hwo = linear & 31;
        size_t idx = (size_t)(b * Cc + c) * N + hw0 + hwo;
        float2 v = xo[idx];
        v.x += g * Ot[c * 33 + hwo];
        v.y += g * Ot[(128 + c) * 33 + hwo];
        xo[idx] = v;
    }
}

extern "C" void kernel_launch(void* const* d_in, const int* in_sizes, int n_in,
                              void* d_out, int out_size, void* d_ws, size_t ws_size,
                              hipStream_t stream) {
    const float* x    = (const float*)d_in[0];
    const float* bn_w = (const float*)d_in[1];
    const float* bn_b = (const float*)d_in[2];
    const float* wq   = (const float*)d_in[3];
    const float* bq   = (const float*)d_in[4];
    const float* wk   = (const float*)d_in[5];
    const float* bk   = (const float*)d_in[6];
    const float* wv   = (const float*)d_in[7];
    const float* bv   = (const float*)d_in[8];
    const float* gam  = (const float*)d_in[9];
    float* out = (float*)d_out;

    char* ws = (char*)d_ws;
    size_t off = 0;
    auto alloc = [&](size_t bytes) -> void* {
        void* p = ws + off;
        off += (bytes + 255) & ~(size_t)255;
        return p;
    };
    float4* ss  = (float4*)alloc(Cc * sizeof(float4));
    char*   XNg = (char*)alloc((size_t)128 * 32768);
    char*   Wg  = (char*)alloc((size_t)12 * 32768);
    float*  bt  = (float*)alloc(768 * 4);
    bf16_t* Qg  = (bf16_t*)alloc((size_t)T * D * 2);
    char*   Kg  = (char*)alloc((size_t)128 * 32768);
    char*   Vg  = (char*)alloc((size_t)128 * 32768);
    bf16_t* Opb = (bf16_t*)alloc((size_t)NSP * T * D * 2);
    float*  Mp  = (float*)alloc((size_t)NSP * T * 4);
    float*  Lp  = (float*)alloc((size_t)NSP * T * 4);

    k_bnstats<<<128, 256, 0, stream>>>(x, bn_w, bn_b, ss);
    k_norm<<<128, 256, 0, stream>>>(x, ss, out, XNg);
    k_prep<<<768, 256, 0, stream>>>(wq, wk, wv, bq, bk, bv, Wg, bt);
    k_qkv<<<dim3(128, 12), 256, 0, stream>>>(XNg, Wg, bt, Qg, Kg, Vg);
    k_attn<<<512, 256, 0, stream>>>(Qg, Kg, Vg, Opb, Mp, Lp);
    k_comb<<<256, 256, 0, stream>>>(Opb, Mp, Lp, gam, out);
}

// Round 3
// 198.875 us; speedup vs baseline: 2.3572x; 2.3572x over previous
//
#include <hip/hip_runtime.h>
#include <hip/hip_bf16.h>

typedef __bf16 bf16_t;
typedef __bf16 bf16x8 __attribute__((ext_vector_type(8)));
typedef float  f32x4  __attribute__((ext_vector_type(4)));

#define MFMA16(A,B,C) __builtin_amdgcn_mfma_f32_16x16x32_bf16((A),(B),(C),0,0,0)

constexpr int Bn = 2, Cc = 128, Hh = 64, Wd = 64;
constexpr int N  = Hh * Wd;      // 4096 tokens per batch
constexpr int T  = Bn * N;       // 8192 tokens total
constexpr int D  = 2 * Cc;       // 256 = [real | imag] channels
constexpr int NSP = 8;           // key splits
constexpr float EPS = 1e-5f;
constexpr float SCL = 0.08838834764831845f * 1.4426950408889634f; // C^-0.5 * log2(e)

// Fragment-ordered 64-row x 256-ch bf16 tile (32 KB): stored as the exact
// sequence of 16x16x32 MFMA fragments. Element (row, ch) lives at:
//   block = (ch>>5)*4 + (row>>4)          (1 KB fragment blocks)
//   inner = ((ch>>3)&3)*16 + (row&15)     (= lane id: quad*16 + n15)
// Every frag read is ds_read_b128 at base + lane*16 -> conflict-free; every
// staging op is an identity global_load_lds copy.
__device__ __forceinline__ int tfrag(int row, int ch) {
    return (((ch >> 5) * 4 + (row >> 4)) << 10) +
           ((((ch >> 3) & 3) * 16 + (row & 15)) << 4) + (ch & 7) * 2;
}
// V tile: 256 ch x 64 keys (keys are the MFMA k-dim), same frag principle.
__device__ __forceinline__ int vfrag(int ch, int key) {
    return (((key >> 5) * 16 + (ch >> 4)) << 10) +
           ((((key >> 3) & 3) * 16 + (ch & 15)) << 4) + (key & 7) * 2;
}

__device__ __forceinline__ void gl16(const void* g, void* l) {
    __builtin_amdgcn_global_load_lds(
        (const __attribute__((address_space(1))) void*)g,
        (__attribute__((address_space(3))) void*)l, 16, 0, 0);
}

// ---------------- kernel 1: BN stats -> per-channel scale/shift ----------------
__global__ void k_bnstats(const float* __restrict__ x, const float* __restrict__ bn_w,
                          const float* __restrict__ bn_b, float4* __restrict__ ss) {
    int c = blockIdx.x;          // 128
    int tid = threadIdx.x;       // 256
    float sr = 0.f, si = 0.f, qr = 0.f, qi = 0.f;
    for (int b = 0; b < Bn; ++b) {
        const float2* p = (const float2*)x + (size_t)(b * Cc + c) * N;
        for (int hw = tid; hw < N; hw += 256) {
            float2 v = p[hw];
            sr += v.x; si += v.y; qr += v.x * v.x; qi += v.y * v.y;
        }
    }
    #pragma unroll
    for (int d = 32; d >= 1; d >>= 1) {
        sr += __shfl_xor(sr, d); si += __shfl_xor(si, d);
        qr += __shfl_xor(qr, d); qi += __shfl_xor(qi, d);
    }
    __shared__ float red[4][4];
    int w = tid >> 6;
    if ((tid & 63) == 0) { red[w][0] = sr; red[w][1] = si; red[w][2] = qr; red[w][3] = qi; }
    __syncthreads();
    if (tid == 0) {
        sr = red[0][0] + red[1][0] + red[2][0] + red[3][0];
        si = red[0][1] + red[1][1] + red[2][1] + red[3][1];
        qr = red[0][2] + red[1][2] + red[2][2] + red[3][2];
        qi = red[0][3] + red[1][3] + red[2][3] + red[3][3];
        const float inv = 1.0f / (float)(Bn * N);
        float mr = sr * inv, mi = si * inv;
        float vr = qr * inv - mr * mr, vi = qi * inv - mi * mi;
        float scr = bn_w[c * 2 + 0] * rsqrtf(vr + EPS);
        float sci = bn_w[c * 2 + 1] * rsqrtf(vi + EPS);
        ss[c] = make_float4(scr, bn_b[c * 2 + 0] - mr * scr,
                            sci, bn_b[c * 2 + 1] - mi * sci);
    }
}

// ---- kernel 2: normalize; xn fp32 -> d_out (residual), bf16 frag tiles -> XNg
__global__ void k_norm(const float* __restrict__ x, const float4* __restrict__ ss,
                       float* __restrict__ xn_out, char* __restrict__ XNg) {
    __shared__ __align__(16) char Tsh[32768];
    int blk = blockIdx.x;        // 128 token tiles
    int b = blk >> 6, hw0 = (blk & 63) * 64;
    int tid = threadIdx.x;
    const float2* xin = (const float2*)x;
    float2* xo = (float2*)xn_out;
    #pragma unroll
    for (int it = 0; it < 32; ++it) {
        int idx = it * 256 + tid;
        int c = idx >> 6, hw = idx & 63;
        size_t gi = (size_t)(b * Cc + c) * N + hw0 + hw;
        float2 v = xin[gi];
        float4 s = ss[c];
        float xr = v.x * s.x + s.y;
        float xi = v.y * s.z + s.w;
        xo[gi] = make_float2(xr, xi);
        *(bf16_t*)(Tsh + tfrag(hw, c))       = (bf16_t)xr;
        *(bf16_t*)(Tsh + tfrag(hw, c + 128)) = (bf16_t)xi;
    }
    __syncthreads();
    #pragma unroll
    for (int it = 0; it < 8; ++it) {
        int idx = it * 256 + tid;
        *(uint4*)(XNg + (size_t)blk * 32768 + idx * 16) = *(const uint4*)(Tsh + idx * 16);
    }
}

// ---- kernel 3: combined weights -> 12 frag tiles [outcol 64][k 256] + bias
__global__ void k_prep(const float* __restrict__ wq, const float* __restrict__ wk,
                       const float* __restrict__ wv, const float* __restrict__ bq,
                       const float* __restrict__ bk, const float* __restrict__ bv,
                       char* __restrict__ Wg, float* __restrict__ bt) {
    int o = blockIdx.x;      // 768 = [Qr Qi Kr Ki Vr Vi] x128
    int k = threadIdx.x;     // 256
    int proj = o >> 8, oc = o & 255;
    const float* wsrc = proj == 0 ? wq : (proj == 1 ? wk : wv);
    const float* bsrc = proj == 0 ? bq : (proj == 1 ? bk : bv);
    int co = oc >> 7, oo = oc & 127;
    int c = k & 127, kc = k >> 7;
    float val;
    if (co == 0) val = (kc == 0) ? wsrc[(oo * 128 + c) * 2 + 0] : -wsrc[(oo * 128 + c) * 2 + 1];
    else         val = (kc == 0) ? wsrc[(oo * 128 + c) * 2 + 1] :  wsrc[(oo * 128 + c) * 2 + 0];
    int tile = o >> 6, row = o & 63;
    *(bf16_t*)(Wg + (size_t)tile * 32768 + tfrag(row, k)) = (bf16_t)val;
    if (k == 0) bt[o] = bsrc[oo * 2 + co];
}

// ---- kernel 4: QKV GEMM [8192x256]@[256x768]; Q/K/V all frag-tile images
__global__ __launch_bounds__(256) void k_qkv(const char* __restrict__ XNg,
        const char* __restrict__ Wg, const float* __restrict__ bt,
        char* __restrict__ Qg, char* __restrict__ Kg, char* __restrict__ Vg) {
    __shared__ __align__(16) char Xsh[32768];
    __shared__ __align__(16) char Wsh[32768];
    int mx = blockIdx.x, ny = blockIdx.y;   // 128 x 12
    int tid = threadIdx.x;
    int w = tid >> 6, lane = tid & 63, n15 = lane & 15, quad = lane >> 4;
    const char* xs = XNg + (size_t)mx * 32768;
    const char* wsp = Wg + (size_t)ny * 32768;
    #pragma unroll
    for (int i = 0; i < 8; ++i) {
        int off = (w * 8 + i) * 1024 + lane * 16;
        gl16(xs + off, Xsh + off);
        gl16(wsp + off, Wsh + off);
    }
    __syncthreads();
    f32x4 acc[4] = {};
    #pragma unroll
    for (int ks = 0; ks < 8; ++ks) {
        bf16x8 a = *(const bf16x8*)(Xsh + (ks * 4 + w) * 1024 + lane * 16);
        #pragma unroll
        for (int t = 0; t < 4; ++t) {
            bf16x8 bw = *(const bf16x8*)(Wsh + (ks * 4 + t) * 1024 + lane * 16);
            acc[t] = MFMA16(a, bw, acc[t]);
        }
    }
    int proj = ny >> 2;            // 0=Q 1=K 2=V
    int jb = (ny & 3) * 64;
    #pragma unroll
    for (int t = 0; t < 4; ++t) {
        int j = jb + t * 16 + n15;
        float bias = bt[ny * 64 + t * 16 + n15];
        #pragma unroll
        for (int r = 0; r < 4; ++r) {
            int tk = mx * 64 + w * 16 + quad * 4 + r;
            float v = acc[t][r] + bias;
            int bb = tk >> 12, n = tk & (N - 1);
            if (proj == 0) {
                *(bf16_t*)(Qg + (size_t)(tk >> 6) * 32768 + tfrag(tk & 63, j)) = (bf16_t)v;
            } else {
                size_t tb = (size_t)(bb * 64 + (n >> 6)) * 32768;
                if (proj == 1) *(bf16_t*)(Kg + tb + tfrag(n & 63, j)) = (bf16_t)v;
                else           *(bf16_t*)(Vg + tb + vfrag(j, n & 63)) = (bf16_t)v;
            }
        }
    }
}

// ---- kernel 5: flash attention. BR=64, BC=64, split 8, 4 waves.
// Wave (r,h): rows r*32..+32; QK on key-half h (32 keys), PV on ch-half h (128 ch).
// Cross-wave softmax (max/sum) via small LDS buffers aliased into Ksh.
__global__ __launch_bounds__(256, 2) void k_attn(const char* __restrict__ Qg,
        const char* __restrict__ Kg, const char* __restrict__ Vg,
        bf16_t* __restrict__ Opb, float* __restrict__ Mp, float* __restrict__ Lp) {
    __shared__ __align__(16) char Ksh[32768];
    __shared__ __align__(16) char Vsh[32768];
    int bid = blockIdx.x;               // 1024 = b(2) x sp(8) x qt(64)
    int qt = bid & 63, sp = (bid >> 6) & 7, b = bid >> 9;
    int tid = threadIdx.x;
    int w = tid >> 6, lane = tid & 63, n15 = lane & 15, quad = lane >> 4;
    int r = w >> 1, h = w & 1;

    // Q fragments: rows qt*64 + r*32 + g*16 (+n15), resident. 64 VGPRs.
    bf16x8 qf[2][8];
    const char* qb = Qg + (size_t)(b * 64 + qt) * 32768;
    #pragma unroll
    for (int g = 0; g < 2; ++g)
        #pragma unroll
        for (int ks = 0; ks < 8; ++ks)
            qf[g][ks] = *(const bf16x8*)(qb + (ks * 4 + r * 2 + g) * 1024 + lane * 16);

    f32x4 o[2][8] = {};                 // 32 rows x 128 ch accumulator (64 regs)
    float m_[2][4], l_[2][4];
    #pragma unroll
    for (int g = 0; g < 2; ++g)
        #pragma unroll
        for (int ri = 0; ri < 4; ++ri) { m_[g][ri] = -1e30f; l_[g][ri] = 0.f; }

    char*  Pb = Ksh;                    // 8 KB: P 64x64 bf16, frag order
    float* pm = (float*)(Ksh + 8192);   // [2][64] partial row max
    float* ps = (float*)(Ksh + 8704);   // [2][64] partial row sum

    for (int kt = 0; kt < 8; ++kt) {
        size_t tb = (size_t)(b * 64 + sp * 8 + kt) * 32768;
        __syncthreads();                              // (A) prev iter consumed
        #pragma unroll
        for (int i = 0; i < 8; ++i) {
            int off = (w * 8 + i) * 1024 + lane * 16;
            gl16(Kg + tb + off, Ksh + off);
            gl16(Vg + tb + off, Vsh + off);
        }
        __syncthreads();                              // (B) staging landed

        // QK^T for this wave's 32 keys (half h): s[g][c] rows g*16.., keys h*32+c*16..
        f32x4 s[2][2] = {};
        #pragma unroll
        for (int ks = 0; ks < 8; ++ks) {
            #pragma unroll
            for (int c = 0; c < 2; ++c) {
                bf16x8 kf = *(const bf16x8*)(Ksh + (ks * 4 + h * 2 + c) * 1024 + lane * 16);
                s[0][c] = MFMA16(qf[0][ks], kf, s[0][c]);
                s[1][c] = MFMA16(qf[1][ks], kf, s[1][c]);
            }
        }
        // partial row max over own 32 keys
        float rmax[2][4];
        #pragma unroll
        for (int g = 0; g < 2; ++g) {
            #pragma unroll
            for (int ri = 0; ri < 4; ++ri)
                rmax[g][ri] = fmaxf(s[g][0][ri], s[g][1][ri]);
            #pragma unroll
            for (int d = 1; d < 16; d <<= 1)
                #pragma unroll
                for (int ri = 0; ri < 4; ++ri)
                    rmax[g][ri] = fmaxf(rmax[g][ri], __shfl_xor(rmax[g][ri], d));
        }
        __syncthreads();                              // (C) K reads done, Ksh reusable
        if (n15 == 0) {
            #pragma unroll
            for (int g = 0; g < 2; ++g)
                #pragma unroll
                for (int ri = 0; ri < 4; ++ri)
                    pm[h * 64 + r * 32 + g * 16 + quad * 4 + ri] = rmax[g][ri];
        }
        __syncthreads();                              // (D) partial max visible
        int need = 0;
        float al[2][4];
        #pragma unroll
        for (int g = 0; g < 2; ++g) {
            f32x4 oth = *(const f32x4*)&pm[(1 - h) * 64 + r * 32 + g * 16 + quad * 4];
            #pragma unroll
            for (int ri = 0; ri < 4; ++ri) {
                float mj = fmaxf(rmax[g][ri], oth[ri]) * SCL;
                float mn = fmaxf(m_[g][ri], mj);
                al[g][ri] = exp2f(m_[g][ri] - mn);
                need |= (mn > m_[g][ri]);
                m_[g][ri] = mn;
            }
        }
        // P = exp2(s*SCL - m), partial sums; write P (frag order) + partial sums
        float rs[2][4];
        #pragma unroll
        for (int g = 0; g < 2; ++g) {
            #pragma unroll
            for (int ri = 0; ri < 4; ++ri) rs[g][ri] = 0.f;
            #pragma unroll
            for (int c = 0; c < 2; ++c)
                #pragma unroll
                for (int ri = 0; ri < 4; ++ri) {
                    float p = exp2f(s[g][c][ri] * SCL - m_[g][ri]);
                    s[g][c][ri] = p;
                    rs[g][ri] += p;
                }
            #pragma unroll
            for (int d = 1; d < 16; d <<= 1)
                #pragma unroll
                for (int ri = 0; ri < 4; ++ri)
                    rs[g][ri] += __shfl_xor(rs[g][ri], d);
            #pragma unroll
            for (int c = 0; c < 2; ++c)
                #pragma unroll
                for (int ri = 0; ri < 4; ++ri)
                    *(bf16_t*)(Pb + (h * 4 + r * 2 + g) * 1024 +
                               (c * 2 + (n15 >> 3)) * 256 + (quad * 4 + ri) * 16 +
                               (n15 & 7) * 2) = (bf16_t)s[g][c][ri];
        }
        if (n15 == 0) {
            #pragma unroll
            for (int g = 0; g < 2; ++g)
                #pragma unroll
                for (int ri = 0; ri < 4; ++ri)
                    ps[h * 64 + r * 32 + g * 16 + quad * 4 + ri] = rs[g][ri];
        }
        __syncthreads();                              // (E) P + partial sums visible
        #pragma unroll
        for (int g = 0; g < 2; ++g) {
            f32x4 oths = *(const f32x4*)&ps[(1 - h) * 64 + r * 32 + g * 16 + quad * 4];
            #pragma unroll
            for (int ri = 0; ri < 4; ++ri)
                l_[g][ri] = l_[g][ri] * al[g][ri] + rs[g][ri] + oths[ri];
        }
        if (__any(need)) {
            #pragma unroll
            for (int g = 0; g < 2; ++g)
                #pragma unroll
                for (int ct = 0; ct < 8; ++ct)
                    #pragma unroll
                    for (int ri = 0; ri < 4; ++ri) o[g][ct][ri] *= al[g][ri];
        }
        // PV: rows r*32.. (full 64 keys), ch half h (128 ch)
        #pragma unroll
        for (int k2 = 0; k2 < 2; ++k2) {
            bf16x8 pa0 = *(const bf16x8*)(Pb + (k2 * 4 + r * 2 + 0) * 1024 + lane * 16);
            bf16x8 pa1 = *(const bf16x8*)(Pb + (k2 * 4 + r * 2 + 1) * 1024 + lane * 16);
            #pragma unroll
            for (int ct = 0; ct < 8; ++ct) {
                bf16x8 bv = *(const bf16x8*)(Vsh + (k2 * 16 + h * 8 + ct) * 1024 + lane * 16);
                o[0][ct] = MFMA16(pa0, bv, o[0][ct]);
                o[1][ct] = MFMA16(pa1, bv, o[1][ct]);
            }
        }
    }
    // epilogue: unnormalized O (bf16) + m, l per split
    int tok0 = b * N + qt * 64 + r * 32;
    #pragma unroll
    for (int g = 0; g < 2; ++g) {
        #pragma unroll
        for (int ct = 0; ct < 8; ++ct)
            #pragma unroll
            for (int ri = 0; ri < 4; ++ri)
                Opb[((size_t)sp * T + tok0 + g * 16 + quad * 4 + ri) * D +
                    h * 128 + ct * 16 + n15] = (bf16_t)o[g][ct][ri];
        if (h == 0 && n15 == 0) {
            #pragma unroll
            for (int ri = 0; ri < 4; ++ri) {
                Mp[sp * T + tok0 + g * 16 + quad * 4 + ri] = m_[g][ri];
                Lp[sp * T + tok0 + g * 16 + quad * 4 + ri] = l_[g][ri];
            }
        }
    }
}

// ---- kernel 6: combine splits, normalize, residual out = xn + gamma * O ----
__global__ void k_comb(const bf16_t* __restrict__ Opb, const float* __restrict__ Mp,
                       const float* __restrict__ Lp, const float* __restrict__ gamma,
                       float* __restrict__ out) {
    __shared__ float wts[NSP][32];
    __shared__ float Ot[256 * 33];
    int blk = blockIdx.x;                // 256 blocks x 32 tokens
    int b = blk >> 7, hw0 = (blk & 127) * 32;
    int tok0 = b * N + hw0;
    int tid = threadIdx.x;
    if (tid < 32) {
        float m[NSP], M = -1e30f;
        #pragma unroll
        for (int s = 0; s < NSP; ++s) { m[s] = Mp[s * T + tok0 + tid]; M = fmaxf(M, m[s]); }
        float Z = 0.f, wv[NSP];
        #pragma unroll
        for (int s = 0; s < NSP; ++s) {
            wv[s] = exp2f(m[s] - M);
            Z += Lp[s * T + tok0 + tid] * wv[s];
        }
        float iz = 1.0f / Z;
        #pragma unroll
        for (int s = 0; s < NSP; ++s) wts[s][tid] = wv[s] * iz;
    }
    __syncthreads();
    #pragma unroll
    for (int i = 0; i < 32; ++i) {
        int idx = i * 256 + tid;
        int tk = idx >> 8, ch = idx & 255;
        size_t base = (size_t)(tok0 + tk) * D + ch;
        float acc = 0.f;
        #pragma unroll
        for (int s = 0; s < NSP; ++s)
            acc += (float)Opb[(size_t)s * T * D + base] * wts[s][tk];
        Ot[ch * 33 + tk] = acc;
    }
    __syncthreads();
    float g = gamma[0];
    float2* xo = (float2*)out;
    #pragma unroll
    for (int i = 0; i < 16; ++i) {
        int linear = i * 256 + tid;
        int c = linear >> 5, hwo = linear & 31;
        size_t idx = (size_t)(b * Cc + c) * N + hw0 + hwo;
        float2 v = xo[idx];
        v.x += g * Ot[c * 33 + hwo];
        v.y += g * Ot[(128 + c) * 33 + hwo];
        xo[idx] = v;
    }
}

extern "C" void kernel_launch(void* const* d_in, const int* in_sizes, int n_in,
                              void* d_out, int out_size, void* d_ws, size_t ws_size,
                              hipStream_t stream) {
    const float* x    = (const float*)d_in[0];
    const float* bn_w = (const float*)d_in[1];
    const float* bn_b = (const float*)d_in[2];
    const float* wq   = (const float*)d_in[3];
    const float* bq   = (const float*)d_in[4];
    const float* wk   = (const float*)d_in[5];
    const float* bk   = (const float*)d_in[6];
    const float* wv   = (const float*)d_in[7];
    const float* bv   = (const float*)d_in[8];
    const float* gam  = (const float*)d_in[9];
    float* out = (float*)d_out;

    char* ws = (char*)d_ws;
    size_t off = 0;
    auto alloc = [&](size_t bytes) -> void* {
        void* p = ws + off;
        off += (bytes + 255) & ~(size_t)255;
        return p;
    };
    float4* ss  = (float4*)alloc(Cc * sizeof(float4));
    char*   XNg = (char*)alloc((size_t)128 * 32768);
    char*   Wg  = (char*)alloc((size_t)12 * 32768);
    float*  bt  = (float*)alloc(768 * 4);
    char*   Qg  = (char*)alloc((size_t)128 * 32768);
    char*   Kg  = (char*)alloc((size_t)128 * 32768);
    char*   Vg  = (char*)alloc((size_t)128 * 32768);
    bf16_t* Opb = (bf16_t*)alloc((size_t)NSP * T * D * 2);
    float*  Mp  = (float*)alloc((size_t)NSP * T * 4);
    float*  Lp  = (float*)alloc((size_t)NSP * T * 4);

    k_bnstats<<<128, 256, 0, stream>>>(x, bn_w, bn_b, ss);
    k_norm<<<128, 256, 0, stream>>>(x, ss, out, XNg);
    k_prep<<<768, 256, 0, stream>>>(wq, wk, wv, bq, bk, bv, Wg, bt);
    k_qkv<<<dim3(128, 12), 256, 0, stream>>>(XNg, Wg, bt, Qg, Kg, Vg);
    k_attn<<<1024, 256, 0, stream>>>(Qg, Kg, Vg, Opb, Mp, Lp);
    k_comb<<<256, 256, 0, stream>>>(Opb, Mp, Lp, gam, out);
}